// Round 1
// baseline (252.601 us; speedup 1.0000x reference)
//
#include <hip/hip_runtime.h>
#include <stdint.h>

typedef unsigned short u16;
typedef __attribute__((ext_vector_type(8))) short bf16x8;
typedef __attribute__((ext_vector_type(4))) float f32x4;

#define B_ 2
#define L_ 2048
#define D_ 1024
#define H_ 16
#define DK_ 64
#define M_ 4096   // B_*L_

__device__ __forceinline__ u16 f2bf(float f) {
    union { float f; uint32_t u; } v; v.f = f;
    uint32_t u = v.u + 0x7fffu + ((v.u >> 16) & 1u);
    return (u16)(u >> 16);
}
__device__ __forceinline__ float bf2f(u16 s) {
    union { uint32_t u; float f; } v; v.u = ((uint32_t)s) << 16;
    return v.f;
}

__device__ __forceinline__ void gld16(const void* g, void* l) {
    __builtin_amdgcn_global_load_lds((const __attribute__((address_space(1))) void*)g,
                                     (__attribute__((address_space(3))) void*)l,
                                     16, 0, 0);
}

// ---------------- pack kernels ----------------

__global__ void cvt_bf16_kernel(const float* __restrict__ s, u16* __restrict__ d, int n4) {
    int i = blockIdx.x * blockDim.x + threadIdx.x;
    const int stride = gridDim.x * blockDim.x;
    for (; i < n4; i += stride) {
        float4 v = ((const float4*)s)[i];
        ushort4 o;
        o.x = f2bf(v.x); o.y = f2bf(v.y); o.z = f2bf(v.z); o.w = f2bf(v.w);
        ((ushort4*)d)[i] = o;
    }
}

// dst[d][k] = src[k][d], both 1024x1024
__global__ void transpose_bf16_kernel(const float* __restrict__ src, u16* __restrict__ dst) {
    __shared__ float tile[32][33];
    const int tx = threadIdx.x, ty = threadIdx.y;
    const int bx = blockIdx.x * 32, by = blockIdx.y * 32;
#pragma unroll
    for (int i = ty; i < 32; i += 8)
        tile[i][tx] = src[(size_t)(by + i) * 1024 + bx + tx];
    __syncthreads();
#pragma unroll
    for (int i = ty; i < 32; i += 8)
        dst[(size_t)(bx + i) * 1024 + by + tx] = f2bf(tile[tx][i]);
}

// ---------------- GEMM (128x128 tile, BK=32, 4 waves) ----------------
// C[M][N] = A[M][K] * Bt[N][K]^T ; K = 1024
// EPI 0: QKV scatter epilogue.  EPI 1: fp32 out + bias.

template <int EPI>
__global__ __launch_bounds__(256) void gemm128(
    const u16* __restrict__ A, const u16* __restrict__ Bt,
    const float* __restrict__ bias0, const float* __restrict__ bias1,
    const float* __restrict__ bias2,
    u16* __restrict__ o_q, u16* __restrict__ o_k, u16* __restrict__ o_vt,
    float* __restrict__ o_f)
{
    constexpr int K = 1024;
    __shared__ u16 As[128 * 32];
    __shared__ u16 Bs[128 * 32];
    const int t = threadIdx.x;
    const int lane = t & 63, w = t >> 6;
    const int wm = w >> 1, wn = w & 1;
    const int g = lane >> 4, r = lane & 15;
    const int mbase = blockIdx.y * 128, nbase = blockIdx.x * 128;

    const f32x4 zero4 = {0.f, 0.f, 0.f, 0.f};
    f32x4 acc[4][4];
#pragma unroll
    for (int m = 0; m < 4; ++m)
#pragma unroll
        for (int n = 0; n < 4; ++n) acc[m][n] = zero4;

    for (int k0 = 0; k0 < K; k0 += 32) {
#pragma unroll
        for (int i = 0; i < 2; ++i) {
            const int base = i * 256 + (w << 6);   // wave-uniform chunk base
            const int idx = base + lane;
            const int row = idx >> 2, cc = (idx & 3) << 3;
            gld16(A + (size_t)(mbase + row) * K + k0 + cc, (char*)As + base * 16);
            gld16(Bt + (size_t)(nbase + row) * K + k0 + cc, (char*)Bs + base * 16);
        }
        __syncthreads();

        bf16x8 af[4], bfr[4];
#pragma unroll
        for (int m = 0; m < 4; ++m)
            af[m] = *(const bf16x8*)&As[(wm * 64 + m * 16 + r) * 32 + g * 8];
#pragma unroll
        for (int n = 0; n < 4; ++n)
            bfr[n] = *(const bf16x8*)&Bs[(wn * 64 + n * 16 + r) * 32 + g * 8];
#pragma unroll
        for (int m = 0; m < 4; ++m)
#pragma unroll
            for (int n = 0; n < 4; ++n)
                acc[m][n] = __builtin_amdgcn_mfma_f32_16x16x32_bf16(af[m], bfr[n], acc[m][n], 0, 0, 0);
        __syncthreads();
    }

#pragma unroll
    for (int m = 0; m < 4; ++m) {
#pragma unroll
        for (int n = 0; n < 4; ++n) {
            const int c = nbase + wn * 64 + n * 16 + r;
#pragma unroll
            for (int j = 0; j < 4; ++j) {
                const int rr = mbase + wm * 64 + m * 16 + g * 4 + j;
                const float y = acc[m][n][j];
                if (EPI == 0) {
                    const int which = c >> 10, d = c & 1023;
                    const int b = rr >> 11, l = rr & 2047;
                    const int h = d >> 6, dd = d & 63;
                    const size_t bh = (size_t)(b * 16 + h);
                    if (which == 0) {
                        o_q[(bh * 2048 + l) * 64 + dd] = f2bf((y + bias0[d]) * 0.125f);
                    } else if (which == 1) {
                        o_k[(bh * 2048 + l) * 64 + dd] = f2bf(y + bias1[d]);
                    } else {
                        o_vt[(bh * 64 + dd) * 2048 + l] = f2bf(y + bias2[d]);
                    }
                } else {
                    o_f[(size_t)rr * 1024 + c] = y + bias0[c];
                }
            }
        }
    }
}

// ---------------- flash attention with bond modulation ----------------
// grid: (L/128, B*H). block: 256 (4 waves), wave w owns q-rows [q0, q0+32)

__global__ __launch_bounds__(256) void attn_kernel(
    const u16* __restrict__ qb, const u16* __restrict__ kb,
    const u16* __restrict__ vtb, const u16* __restrict__ bondb,
    u16* __restrict__ attnout)
{
    __shared__ u16 Ks[64 * 64];      // [key][dk]
    __shared__ u16 Vs[64 * 64];      // [dk][key]
    __shared__ u16 Ps[4][32 * 64];   // per-wave P tile [q][key]
    const int t = threadIdx.x;
    const int lane = t & 63, w = t >> 6;
    const int g = lane >> 4, r = lane & 15;
    const int bh = blockIdx.y;
    const int b = bh >> 4, h = bh & 15;
    const int q0 = blockIdx.x * 128 + w * 32;
    const size_t qkvBase = (size_t)bh * 2048 * 64;
    const f32x4 zero4 = {0.f, 0.f, 0.f, 0.f};

    // Q fragments in registers (A-operand layout: row = lane&15, k = (lane>>4)*8+j)
    bf16x8 aq[2][2];
#pragma unroll
    for (int m = 0; m < 2; ++m)
#pragma unroll
        for (int ks = 0; ks < 2; ++ks)
            aq[m][ks] = *(const bf16x8*)&qb[qkvBase + (size_t)(q0 + m * 16 + r) * 64 + ks * 32 + g * 8];

    float mrun[2][4], lrun[2][4];
    f32x4 o[2][4];
#pragma unroll
    for (int m = 0; m < 2; ++m) {
#pragma unroll
        for (int j = 0; j < 4; ++j) { mrun[m][j] = -1e30f; lrun[m][j] = 0.f; }
#pragma unroll
        for (int nf = 0; nf < 4; ++nf) o[m][nf] = zero4;
    }

    for (int kt = 0; kt < 2048; kt += 64) {
#pragma unroll
        for (int i = 0; i < 2; ++i) {
            const int base = i * 256 + (w << 6);
            const int idx = base + lane;
            const int row = idx >> 3, ch = idx & 7;
            gld16(kb + qkvBase + (size_t)(kt + row) * 64 + ch * 8, (char*)Ks + base * 16);
            gld16(vtb + (size_t)(bh * 64 + row) * 2048 + kt + ch * 8, (char*)Vs + base * 16);
        }
        __syncthreads();

        // S = Q * K^T  (pre-scaled by 1/8 via Q)
        f32x4 s[2][4];
#pragma unroll
        for (int m = 0; m < 2; ++m)
#pragma unroll
            for (int n = 0; n < 4; ++n) s[m][n] = zero4;
#pragma unroll
        for (int ks = 0; ks < 2; ++ks) {
            bf16x8 bk_[4];
#pragma unroll
            for (int n = 0; n < 4; ++n)
                bk_[n] = *(const bf16x8*)&Ks[(n * 16 + r) * 64 + ks * 32 + g * 8];
#pragma unroll
            for (int m = 0; m < 2; ++m)
#pragma unroll
                for (int n = 0; n < 4; ++n)
                    s[m][n] = __builtin_amdgcn_mfma_f32_16x16x32_bf16(aq[m][ks], bk_[n], s[m][n], 0, 0, 0);
        }

        // bond modulation (fp32)
        float p[2][4][4];
#pragma unroll
        for (int m = 0; m < 2; ++m) {
#pragma unroll
            for (int j = 0; j < 4; ++j) {
                const size_t brow = ((size_t)b * 2048 + (q0 + m * 16 + g * 4 + j)) * 2048 + kt;
#pragma unroll
                for (int n = 0; n < 4; ++n)
                    p[m][n][j] = s[m][n][j] * bf2f(bondb[brow + n * 16 + r]);
            }
        }

        // online softmax (row = (lane>>4)*4+j, cols across 16 lanes & 4 frags)
#pragma unroll
        for (int m = 0; m < 2; ++m) {
            float mx[4], sm[4];
#pragma unroll
            for (int j = 0; j < 4; ++j)
                mx[j] = fmaxf(fmaxf(p[m][0][j], p[m][1][j]), fmaxf(p[m][2][j], p[m][3][j]));
#pragma unroll
            for (int mask = 1; mask < 16; mask <<= 1)
#pragma unroll
                for (int j = 0; j < 4; ++j)
                    mx[j] = fmaxf(mx[j], __shfl_xor(mx[j], mask, 64));
#pragma unroll
            for (int j = 0; j < 4; ++j) {
                const float mnew = fmaxf(mrun[m][j], mx[j]);
                const float fs = __expf(mrun[m][j] - mnew);
                mrun[m][j] = mnew;
                lrun[m][j] *= fs;
#pragma unroll
                for (int nf = 0; nf < 4; ++nf) o[m][nf][j] *= fs;
                sm[j] = 0.f;
            }
#pragma unroll
            for (int n = 0; n < 4; ++n)
#pragma unroll
                for (int j = 0; j < 4; ++j) {
                    const float pv = __expf(p[m][n][j] - mrun[m][j]);
                    p[m][n][j] = pv;
                    sm[j] += pv;
                }
#pragma unroll
            for (int mask = 1; mask < 16; mask <<= 1)
#pragma unroll
                for (int j = 0; j < 4; ++j)
                    sm[j] += __shfl_xor(sm[j], mask, 64);
#pragma unroll
            for (int j = 0; j < 4; ++j) lrun[m][j] += sm[j];
            // P -> LDS (bf16), D-layout write
#pragma unroll
            for (int n = 0; n < 4; ++n)
#pragma unroll
                for (int j = 0; j < 4; ++j)
                    Ps[w][(m * 16 + g * 4 + j) * 64 + n * 16 + r] = f2bf(p[m][n][j]);
        }

        // O += P * V   (A from Ps, B from Vs[dk][key])
#pragma unroll
        for (int ks = 0; ks < 2; ++ks) {
            bf16x8 ap[2], bv_[4];
#pragma unroll
            for (int m = 0; m < 2; ++m)
                ap[m] = *(const bf16x8*)&Ps[w][(m * 16 + r) * 64 + ks * 32 + g * 8];
#pragma unroll
            for (int nf = 0; nf < 4; ++nf)
                bv_[nf] = *(const bf16x8*)&Vs[(nf * 16 + r) * 64 + ks * 32 + g * 8];
#pragma unroll
            for (int m = 0; m < 2; ++m)
#pragma unroll
                for (int nf = 0; nf < 4; ++nf)
                    o[m][nf] = __builtin_amdgcn_mfma_f32_16x16x32_bf16(ap[m], bv_[nf], o[m][nf], 0, 0, 0);
        }
        __syncthreads();
    }

    // write attnout [b*2048+q][h*64+dd] bf16
#pragma unroll
    for (int m = 0; m < 2; ++m)
#pragma unroll
        for (int j = 0; j < 4; ++j) {
            const float inv = 1.f / lrun[m][j];
            const size_t orow = ((size_t)b * 2048 + (q0 + m * 16 + g * 4 + j)) * 1024 + h * 64;
#pragma unroll
            for (int nf = 0; nf < 4; ++nf)
                attnout[orow + nf * 16 + r] = f2bf(o[m][nf][j] * inv);
        }
}

// ---------------- launch ----------------

extern "C" void kernel_launch(void* const* d_in, const int* in_sizes, int n_in,
                              void* d_out, int out_size, void* d_ws, size_t ws_size,
                              hipStream_t stream) {
    (void)in_sizes; (void)n_in; (void)out_size; (void)ws_size;
    const float* x    = (const float*)d_in[0];
    const float* bond = (const float*)d_in[1];
    const float* Wq   = (const float*)d_in[2];
    const float* bq   = (const float*)d_in[3];
    const float* Wk   = (const float*)d_in[4];
    const float* bk   = (const float*)d_in[5];
    const float* Wv   = (const float*)d_in[6];
    const float* bv   = (const float*)d_in[7];
    const float* Wo   = (const float*)d_in[8];
    const float* bo   = (const float*)d_in[9];
    float* out = (float*)d_out;

    char* ws = (char*)d_ws;
    u16* xb      = (u16*)(ws);
    u16* wqkvt   = (u16*)(ws + 8388608);
    u16* wot     = (u16*)(ws + 14680064);
    u16* qb      = (u16*)(ws + 16777216);
    u16* kb_     = (u16*)(ws + 25165824);
    u16* vtb     = (u16*)(ws + 33554432);
    u16* bondb   = (u16*)(ws + 41943040);
    u16* attnout = (u16*)(ws + 58720256);

    dim3 tb(32, 8);
    transpose_bf16_kernel<<<dim3(32, 32), tb, 0, stream>>>(Wq, wqkvt);
    transpose_bf16_kernel<<<dim3(32, 32), tb, 0, stream>>>(Wk, wqkvt + 1024 * 1024);
    transpose_bf16_kernel<<<dim3(32, 32), tb, 0, stream>>>(Wv, wqkvt + 2 * 1024 * 1024);
    transpose_bf16_kernel<<<dim3(32, 32), tb, 0, stream>>>(Wo, wot);
    cvt_bf16_kernel<<<1024, 256, 0, stream>>>(x, xb, 4194304 / 4);
    cvt_bf16_kernel<<<2048, 256, 0, stream>>>(bond, bondb, 8388608 / 4);

    gemm128<0><<<dim3(24, 32), 256, 0, stream>>>(xb, wqkvt, bq, bk, bv, qb, kb_, vtb, nullptr);
    attn_kernel<<<dim3(16, 32), 256, 0, stream>>>(qb, kb_, vtb, bondb, attnout);
    gemm128<1><<<dim3(8, 32), 256, 0, stream>>>(attnout, wot, bo, nullptr, nullptr,
                                                nullptr, nullptr, nullptr, out);
}

// Round 2
// 194.667 us; speedup vs baseline: 1.2976x; 1.2976x over previous
//
#include <hip/hip_runtime.h>
#include <stdint.h>

typedef unsigned short u16;
typedef __attribute__((ext_vector_type(8))) short bf16x8;
typedef __attribute__((ext_vector_type(4))) float f32x4;

__device__ __forceinline__ u16 f2bf(float f) {
    union { float f; uint32_t u; } v; v.f = f;
    uint32_t u = v.u + 0x7fffu + ((v.u >> 16) & 1u);
    return (u16)(u >> 16);
}
__device__ __forceinline__ float bf2f(u16 s) {
    union { uint32_t u; float f; } v; v.u = ((uint32_t)s) << 16;
    return v.f;
}
// fast positive-value pack: round-half-up (bias only on exact ties)
__device__ __forceinline__ uint32_t packbf(float a, float b) {
    union { float f; uint32_t u; } ua, ub; ua.f = a; ub.f = b;
    return ((ua.u + 0x8000u) >> 16) | ((ub.u + 0x8000u) & 0xffff0000u);
}

__device__ __forceinline__ void gld16(const void* g, void* l) {
    __builtin_amdgcn_global_load_lds((const __attribute__((address_space(1))) void*)g,
                                     (__attribute__((address_space(3))) void*)l,
                                     16, 0, 0);
}

// ---------------- pack kernels ----------------

__global__ void cvt_bf16_kernel(const float* __restrict__ s, u16* __restrict__ d, int n4) {
    int i = blockIdx.x * blockDim.x + threadIdx.x;
    const int stride = gridDim.x * blockDim.x;
    for (; i < n4; i += stride) {
        float4 v = ((const float4*)s)[i];
        ushort4 o;
        o.x = f2bf(v.x); o.y = f2bf(v.y); o.z = f2bf(v.z); o.w = f2bf(v.w);
        ((ushort4*)d)[i] = o;
    }
}

// dst[d][k] = src[k][d], both 1024x1024
__global__ void transpose_bf16_kernel(const float* __restrict__ src, u16* __restrict__ dst) {
    __shared__ float tile[32][33];
    const int tx = threadIdx.x, ty = threadIdx.y;
    const int bx = blockIdx.x * 32, by = blockIdx.y * 32;
#pragma unroll
    for (int i = ty; i < 32; i += 8)
        tile[i][tx] = src[(size_t)(by + i) * 1024 + bx + tx];
    __syncthreads();
#pragma unroll
    for (int i = ty; i < 32; i += 8)
        dst[(size_t)(bx + i) * 1024 + by + tx] = f2bf(tile[tx][i]);
}

// ---------------- GEMM (128x128 tile, BK=32, 4 waves) ----------------

template <int EPI>
__global__ __launch_bounds__(256) void gemm128(
    const u16* __restrict__ A, const u16* __restrict__ Bt,
    const float* __restrict__ bias0, const float* __restrict__ bias1,
    const float* __restrict__ bias2,
    u16* __restrict__ o_q, u16* __restrict__ o_k, u16* __restrict__ o_vt,
    float* __restrict__ o_f)
{
    constexpr int K = 1024;
    __shared__ u16 As[128 * 32];
    __shared__ u16 Bs[128 * 32];
    const int t = threadIdx.x;
    const int lane = t & 63, w = t >> 6;
    const int wm = w >> 1, wn = w & 1;
    const int g = lane >> 4, r = lane & 15;
    const int mbase = blockIdx.y * 128, nbase = blockIdx.x * 128;

    const f32x4 zero4 = {0.f, 0.f, 0.f, 0.f};
    f32x4 acc[4][4];
#pragma unroll
    for (int m = 0; m < 4; ++m)
#pragma unroll
        for (int n = 0; n < 4; ++n) acc[m][n] = zero4;

    for (int k0 = 0; k0 < K; k0 += 32) {
#pragma unroll
        for (int i = 0; i < 2; ++i) {
            const int base = i * 256 + (w << 6);
            const int idx = base + lane;
            const int row = idx >> 2, cc = (idx & 3) << 3;
            gld16(A + (size_t)(mbase + row) * K + k0 + cc, (char*)As + base * 16);
            gld16(Bt + (size_t)(nbase + row) * K + k0 + cc, (char*)Bs + base * 16);
        }
        __syncthreads();

        bf16x8 af[4], bfr[4];
#pragma unroll
        for (int m = 0; m < 4; ++m)
            af[m] = *(const bf16x8*)&As[(wm * 64 + m * 16 + r) * 32 + g * 8];
#pragma unroll
        for (int n = 0; n < 4; ++n)
            bfr[n] = *(const bf16x8*)&Bs[(wn * 64 + n * 16 + r) * 32 + g * 8];
#pragma unroll
        for (int m = 0; m < 4; ++m)
#pragma unroll
            for (int n = 0; n < 4; ++n)
                acc[m][n] = __builtin_amdgcn_mfma_f32_16x16x32_bf16(af[m], bfr[n], acc[m][n], 0, 0, 0);
        __syncthreads();
    }

#pragma unroll
    for (int m = 0; m < 4; ++m) {
#pragma unroll
        for (int n = 0; n < 4; ++n) {
            const int c = nbase + wn * 64 + n * 16 + r;
#pragma unroll
            for (int j = 0; j < 4; ++j) {
                const int rr = mbase + wm * 64 + m * 16 + g * 4 + j;
                const float y = acc[m][n][j];
                if (EPI == 0) {
                    const int which = c >> 10, d = c & 1023;
                    const int b = rr >> 11, l = rr & 2047;
                    const int h = d >> 6, dd = d & 63;
                    const size_t bh = (size_t)(b * 16 + h);
                    if (which == 0) {
                        o_q[(bh * 2048 + l) * 64 + dd] = f2bf((y + bias0[d]) * 0.125f);
                    } else if (which == 1) {
                        o_k[(bh * 2048 + l) * 64 + dd] = f2bf(y + bias1[d]);
                    } else {
                        o_vt[(bh * 64 + dd) * 2048 + l] = f2bf(y + bias2[d]);
                    }
                } else {
                    o_f[(size_t)rr * 1024 + c] = y + bias0[c];
                }
            }
        }
    }
}

// ---------------- flash attention v2: swapped QK^T, no-max softmax ----------------
// grid: 1024 flat (32 q-tiles x 32 bh, XCD-swizzled). block: 128 (2 waves).
// Wave w owns 32 q-rows. LDS: K/V double-buffered + per-wave P = 40 KB exactly.

__global__ __launch_bounds__(128, 2) void attn_kernel(
    const u16* __restrict__ qb, const u16* __restrict__ kb,
    const u16* __restrict__ vtb, const u16* __restrict__ bondb,
    u16* __restrict__ attnout)
{
    __shared__ u16 Ks[2][64 * 64];   // [buf][key][dk]   swizzled chunks
    __shared__ u16 Vs[2][64 * 64];   // [buf][dk][key]   swizzled chunks
    __shared__ u16 Ps[2][32 * 64];   // [wave][q][key]   swizzled chunks
    const int t = threadIdx.x;
    const int lane = t & 63, w = t >> 6;
    const int g = lane >> 4, r = lane & 15;
    const int sw = r & 7;
    // XCD-aware swizzle: 128 consecutive wg per XCD -> 4 bh (one b) per XCD
    const int flat = blockIdx.x;
    const int wg = (flat & 7) * 128 + (flat >> 3);
    const int bh = wg >> 5, qt = wg & 31;
    const int b = bh >> 4, h = bh & 15;
    const int q0 = qt * 64 + w * 32;
    const size_t kvBase = (size_t)bh * 2048 * 64;

    // Q as B-operand fragments: lane gives Q[q0+qf*16+r][kz*32+g*8+j]
    bf16x8 aq[2][2];
#pragma unroll
    for (int qf = 0; qf < 2; ++qf)
#pragma unroll
        for (int kz = 0; kz < 2; ++kz)
            aq[qf][kz] = *(const bf16x8*)&qb[kvBase + (size_t)(q0 + qf * 16 + r) * 64 + kz * 32 + g * 8];

    const f32x4 zero4 = {0.f, 0.f, 0.f, 0.f};
    f32x4 o[2][4];
#pragma unroll
    for (int qf = 0; qf < 2; ++qf)
#pragma unroll
        for (int nf = 0; nf < 4; ++nf) o[qf][nf] = zero4;
    float sm[2] = {0.f, 0.f};

    // prologue: stage tile 0 (pre-swizzled source, linear LDS dest)
#pragma unroll
    for (int i = 0; i < 4; ++i) {
        const int idx = i * 128 + t;
        const int row = idx >> 3, ch = idx & 7;
        const int chg = ch ^ (row & 7);
        gld16(kb + kvBase + (size_t)row * 64 + chg * 8, (char*)&Ks[0][0] + idx * 16);
        gld16(vtb + ((size_t)bh * 64 + row) * 2048 + chg * 8, (char*)&Vs[0][0] + idx * 16);
    }
    __syncthreads();

    for (int it = 0; it < 32; ++it) {
        const int cur = it & 1;
        const int kt = it * 64;
        // prefetch next K/V tile into other buffer (stays in flight during compute)
        if (it < 31) {
            const int kt2 = kt + 64;
#pragma unroll
            for (int i = 0; i < 4; ++i) {
                const int idx = i * 128 + t;
                const int row = idx >> 3, ch = idx & 7;
                const int chg = ch ^ (row & 7);
                gld16(kb + kvBase + (size_t)(kt2 + row) * 64 + chg * 8, (char*)&Ks[cur ^ 1][0] + idx * 16);
                gld16(vtb + ((size_t)bh * 64 + row) * 2048 + kt2 + chg * 8, (char*)&Vs[cur ^ 1][0] + idx * 16);
            }
        }
        // bond loads: vectorized ushort4, one q-row per lane
        ushort4 bd[2][4];
#pragma unroll
        for (int qf = 0; qf < 2; ++qf)
#pragma unroll
            for (int kf = 0; kf < 4; ++kf)
                bd[qf][kf] = *(const ushort4*)&bondb[((size_t)b * 2048 + q0 + qf * 16 + r) * 2048 + kt + kf * 16 + g * 4];

        // S^T = mfma(K, Q): key = kf*16+g*4+jj (rows), q = qf*16+r (cols)
        f32x4 st[2][4];
#pragma unroll
        for (int qf = 0; qf < 2; ++qf)
#pragma unroll
            for (int kf = 0; kf < 4; ++kf) st[qf][kf] = zero4;
#pragma unroll
        for (int kz = 0; kz < 2; ++kz) {
            bf16x8 kfr[4];
#pragma unroll
            for (int kf = 0; kf < 4; ++kf)
                kfr[kf] = *(const bf16x8*)((const char*)&Ks[cur][0] +
                            (kf * 16 + r) * 128 + (((kz * 4 + g) ^ sw) * 16));
#pragma unroll
            for (int qf = 0; qf < 2; ++qf)
#pragma unroll
                for (int kf = 0; kf < 4; ++kf)
                    st[qf][kf] = __builtin_amdgcn_mfma_f32_16x16x32_bf16(kfr[kf], aq[qf][kz], st[qf][kf], 0, 0, 0);
        }

        // p = exp(s*bond); lane-local row-sum; packed b64 write to P (swizzled)
#pragma unroll
        for (int qf = 0; qf < 2; ++qf) {
#pragma unroll
            for (int kf = 0; kf < 4; ++kf) {
                const float p0 = __expf(st[qf][kf][0] * bf2f(bd[qf][kf].x));
                const float p1 = __expf(st[qf][kf][1] * bf2f(bd[qf][kf].y));
                const float p2 = __expf(st[qf][kf][2] * bf2f(bd[qf][kf].z));
                const float p3 = __expf(st[qf][kf][3] * bf2f(bd[qf][kf].w));
                sm[qf] += (p0 + p1) + (p2 + p3);
                uint2 pk;
                pk.x = packbf(p0, p1);
                pk.y = packbf(p2, p3);
                *(uint2*)((char*)&Ps[w][0] + (qf * 16 + r) * 128 + ((kf * 32 + g * 8) ^ (sw << 4))) = pk;
            }
        }

        // O += P * V : A = P[q][key] from LDS, B = V[key][dk] from Vs ([dk][key] rows)
#pragma unroll
        for (int kz = 0; kz < 2; ++kz) {
            bf16x8 ap[2], bv_[4];
#pragma unroll
            for (int qf = 0; qf < 2; ++qf)
                ap[qf] = *(const bf16x8*)((const char*)&Ps[w][0] +
                            (qf * 16 + r) * 128 + ((kz * 64 + g * 16) ^ (sw << 4)));
#pragma unroll
            for (int nf = 0; nf < 4; ++nf)
                bv_[nf] = *(const bf16x8*)((const char*)&Vs[cur][0] +
                            (nf * 16 + r) * 128 + (((kz * 4 + g) ^ sw) * 16));
#pragma unroll
            for (int qf = 0; qf < 2; ++qf)
#pragma unroll
                for (int nf = 0; nf < 4; ++nf)
                    o[qf][nf] = __builtin_amdgcn_mfma_f32_16x16x32_bf16(ap[qf], bv_[nf], o[qf][nf], 0, 0, 0);
        }
        __syncthreads();
    }

    // final row-sum reduce across the 4 g-groups (deferred, once)
#pragma unroll
    for (int qf = 0; qf < 2; ++qf) {
        sm[qf] += __shfl_xor(sm[qf], 16, 64);
        sm[qf] += __shfl_xor(sm[qf], 32, 64);
    }
    // redistribute sums to the O-accumulator lane layout via per-wave LDS (reuse Ps)
    float* Lw = (float*)&Ps[w][0];
    if (g == 0) { Lw[r] = sm[0]; Lw[16 + r] = sm[1]; }
    __syncthreads();
    f32x4 lv[2];
    lv[0] = *(const f32x4*)&Lw[g * 4];
    lv[1] = *(const f32x4*)&Lw[16 + g * 4];

#pragma unroll
    for (int qf = 0; qf < 2; ++qf)
#pragma unroll
        for (int j = 0; j < 4; ++j) {
            const float inv = 1.f / lv[qf][j];
            const size_t orow = ((size_t)b * 2048 + q0 + qf * 16 + g * 4 + j) * 1024 + h * 64;
#pragma unroll
            for (int nf = 0; nf < 4; ++nf)
                attnout[orow + nf * 16 + r] = f2bf(o[qf][nf][j] * inv);
        }
}

// ---------------- launch ----------------

extern "C" void kernel_launch(void* const* d_in, const int* in_sizes, int n_in,
                              void* d_out, int out_size, void* d_ws, size_t ws_size,
                              hipStream_t stream) {
    (void)in_sizes; (void)n_in; (void)out_size; (void)ws_size;
    const float* x    = (const float*)d_in[0];
    const float* bond = (const float*)d_in[1];
    const float* Wq   = (const float*)d_in[2];
    const float* bq   = (const float*)d_in[3];
    const float* Wk   = (const float*)d_in[4];
    const float* bk   = (const float*)d_in[5];
    const float* Wv   = (const float*)d_in[6];
    const float* bv   = (const float*)d_in[7];
    const float* Wo   = (const float*)d_in[8];
    const float* bo   = (const float*)d_in[9];
    float* out = (float*)d_out;

    char* ws = (char*)d_ws;
    u16* xb      = (u16*)(ws);
    u16* wqkvt   = (u16*)(ws + 8388608);
    u16* wot     = (u16*)(ws + 14680064);
    u16* qb      = (u16*)(ws + 16777216);
    u16* kb_     = (u16*)(ws + 25165824);
    u16* vtb     = (u16*)(ws + 33554432);
    u16* bondb   = (u16*)(ws + 41943040);
    u16* attnout = (u16*)(ws + 58720256);

    dim3 tb(32, 8);
    transpose_bf16_kernel<<<dim3(32, 32), tb, 0, stream>>>(Wq, wqkvt);
    transpose_bf16_kernel<<<dim3(32, 32), tb, 0, stream>>>(Wk, wqkvt + 1024 * 1024);
    transpose_bf16_kernel<<<dim3(32, 32), tb, 0, stream>>>(Wv, wqkvt + 2 * 1024 * 1024);
    transpose_bf16_kernel<<<dim3(32, 32), tb, 0, stream>>>(Wo, wot);
    cvt_bf16_kernel<<<1024, 256, 0, stream>>>(x, xb, 4194304 / 4);
    cvt_bf16_kernel<<<2048, 256, 0, stream>>>(bond, bondb, 8388608 / 4);

    gemm128<0><<<dim3(24, 32), 256, 0, stream>>>(xb, wqkvt, bq, bk, bv, qb, kb_, vtb, nullptr);
    attn_kernel<<<dim3(1024), 128, 0, stream>>>(qb, kb_, vtb, bondb, attnout);
    gemm128<1><<<dim3(8, 32), 256, 0, stream>>>(attnout, wot, bo, nullptr, nullptr,
                                                nullptr, nullptr, nullptr, out);
}

// Round 3
// 171.769 us; speedup vs baseline: 1.4706x; 1.1333x over previous
//
#include <hip/hip_runtime.h>
#include <stdint.h>

typedef unsigned short u16;
typedef __attribute__((ext_vector_type(8))) short bf16x8;
typedef __attribute__((ext_vector_type(4))) float f32x4;

__device__ __forceinline__ u16 f2bf(float f) {
    union { float f; uint32_t u; } v; v.f = f;
    uint32_t u = v.u + 0x7fffu + ((v.u >> 16) & 1u);
    return (u16)(u >> 16);
}
__device__ __forceinline__ float bf2f(u16 s) {
    union { uint32_t u; float f; } v; v.u = ((uint32_t)s) << 16;
    return v.f;
}
// fast positive-value pack: round-half-up (bias only on exact ties)
__device__ __forceinline__ uint32_t packbf(float a, float b) {
    union { float f; uint32_t u; } ua, ub; ua.f = a; ub.f = b;
    return ((ua.u + 0x8000u) >> 16) | ((ub.u + 0x8000u) & 0xffff0000u);
}

__device__ __forceinline__ void gld16(const void* g, void* l) {
    __builtin_amdgcn_global_load_lds((const __attribute__((address_space(1))) void*)g,
                                     (__attribute__((address_space(3))) void*)l,
                                     16, 0, 0);
}

// ---------------- pack kernels ----------------

__global__ void cvt_bf16_kernel(const float* __restrict__ s, u16* __restrict__ d, int n4) {
    int i = blockIdx.x * blockDim.x + threadIdx.x;
    const int stride = gridDim.x * blockDim.x;
    for (; i < n4; i += stride) {
        float4 v = ((const float4*)s)[i];
        ushort4 o;
        o.x = f2bf(v.x); o.y = f2bf(v.y); o.z = f2bf(v.z); o.w = f2bf(v.w);
        ((ushort4*)d)[i] = o;
    }
}

// dst[d][k] = src[k][d], both 1024x1024
__global__ void transpose_bf16_kernel(const float* __restrict__ src, u16* __restrict__ dst) {
    __shared__ float tile[32][33];
    const int tx = threadIdx.x, ty = threadIdx.y;
    const int bx = blockIdx.x * 32, by = blockIdx.y * 32;
#pragma unroll
    for (int i = ty; i < 32; i += 8)
        tile[i][tx] = src[(size_t)(by + i) * 1024 + bx + tx];
    __syncthreads();
#pragma unroll
    for (int i = ty; i < 32; i += 8)
        dst[(size_t)(bx + i) * 1024 + by + tx] = f2bf(tile[tx][i]);
}

// ---------------- GEMM (128x128 tile, BK=32, 4 waves) ----------------

template <int EPI>
__global__ __launch_bounds__(256) void gemm128(
    const u16* __restrict__ A, const u16* __restrict__ Bt,
    const float* __restrict__ bias0, const float* __restrict__ bias1,
    const float* __restrict__ bias2,
    u16* __restrict__ o_q, u16* __restrict__ o_k, u16* __restrict__ o_vt,
    float* __restrict__ o_f)
{
    constexpr int K = 1024;
    __shared__ u16 As[128 * 32];
    __shared__ u16 Bs[128 * 32];
    const int t = threadIdx.x;
    const int lane = t & 63, w = t >> 6;
    const int wm = w >> 1, wn = w & 1;
    const int g = lane >> 4, r = lane & 15;
    const int mbase = blockIdx.y * 128, nbase = blockIdx.x * 128;

    const f32x4 zero4 = {0.f, 0.f, 0.f, 0.f};
    f32x4 acc[4][4];
#pragma unroll
    for (int m = 0; m < 4; ++m)
#pragma unroll
        for (int n = 0; n < 4; ++n) acc[m][n] = zero4;

    for (int k0 = 0; k0 < K; k0 += 32) {
#pragma unroll
        for (int i = 0; i < 2; ++i) {
            const int base = i * 256 + (w << 6);
            const int idx = base + lane;
            const int row = idx >> 2, cc = (idx & 3) << 3;
            gld16(A + (size_t)(mbase + row) * K + k0 + cc, (char*)As + base * 16);
            gld16(Bt + (size_t)(nbase + row) * K + k0 + cc, (char*)Bs + base * 16);
        }
        __syncthreads();

        bf16x8 af[4], bfr[4];
#pragma unroll
        for (int m = 0; m < 4; ++m)
            af[m] = *(const bf16x8*)&As[(wm * 64 + m * 16 + r) * 32 + g * 8];
#pragma unroll
        for (int n = 0; n < 4; ++n)
            bfr[n] = *(const bf16x8*)&Bs[(wn * 64 + n * 16 + r) * 32 + g * 8];
        __builtin_amdgcn_s_setprio(1);
#pragma unroll
        for (int m = 0; m < 4; ++m)
#pragma unroll
            for (int n = 0; n < 4; ++n)
                acc[m][n] = __builtin_amdgcn_mfma_f32_16x16x32_bf16(af[m], bfr[n], acc[m][n], 0, 0, 0);
        __builtin_amdgcn_s_setprio(0);
        __syncthreads();
    }

#pragma unroll
    for (int m = 0; m < 4; ++m) {
#pragma unroll
        for (int n = 0; n < 4; ++n) {
            const int c = nbase + wn * 64 + n * 16 + r;
#pragma unroll
            for (int j = 0; j < 4; ++j) {
                const int rr = mbase + wm * 64 + m * 16 + g * 4 + j;
                const float y = acc[m][n][j];
                if (EPI == 0) {
                    const int which = c >> 10, d = c & 1023;
                    const int b = rr >> 11, l = rr & 2047;
                    const int h = d >> 6, dd = d & 63;
                    const size_t bh = (size_t)(b * 16 + h);
                    if (which == 0) {
                        o_q[(bh * 2048 + l) * 64 + dd] = f2bf((y + bias0[d]) * 0.125f);
                    } else if (which == 1) {
                        o_k[(bh * 2048 + l) * 64 + dd] = f2bf(y + bias1[d]);
                    } else {
                        o_vt[(bh * 64 + dd) * 2048 + l] = f2bf(y + bias2[d]);
                    }
                } else {
                    o_f[(size_t)rr * 1024 + c] = y + bias0[c];
                }
            }
        }
    }
}

// ---------------- flash attention v3: interleaved phases, bond reg-prefetch ----------------
// grid: 1024 flat (32 q-tiles x 32 bh, XCD-swizzled). block: 128 (2 waves).

__global__ __launch_bounds__(128, 2) void attn_kernel(
    const u16* __restrict__ qb, const u16* __restrict__ kb,
    const u16* __restrict__ vtb, const float* __restrict__ bondf,
    u16* __restrict__ attnout)
{
    __shared__ u16 Ks[2][64 * 64];   // [buf][key][dk]   swizzled chunks
    __shared__ u16 Vs[2][64 * 64];   // [buf][dk][key]   swizzled chunks
    __shared__ u16 Ps[2][32 * 64];   // [wave][q][key]   swizzled chunks
    const int t = threadIdx.x;
    const int lane = t & 63, w = t >> 6;
    const int g = lane >> 4, r = lane & 15;
    const int sw = r & 7;
    const int flat = blockIdx.x;
    const int wg = (flat & 7) * 128 + (flat >> 3);
    const int bh = wg >> 5, qt = wg & 31;
    const int b = bh >> 4, h = bh & 15;
    const int q0 = qt * 64 + w * 32;
    const size_t kvBase = (size_t)bh * 2048 * 64;
    const size_t bondRow0 = ((size_t)b * 2048 + q0 + r) * 2048;   // qf adds 16*2048

    // Q as B-operand fragments
    bf16x8 aq[2][2];
#pragma unroll
    for (int qf = 0; qf < 2; ++qf)
#pragma unroll
        for (int kz = 0; kz < 2; ++kz)
            aq[qf][kz] = *(const bf16x8*)&qb[kvBase + (size_t)(q0 + qf * 16 + r) * 64 + kz * 32 + g * 8];

    const f32x4 zero4 = {0.f, 0.f, 0.f, 0.f};
    f32x4 o[2][4];
#pragma unroll
    for (int qf = 0; qf < 2; ++qf)
#pragma unroll
        for (int nf = 0; nf < 4; ++nf) o[qf][nf] = zero4;
    float sm[2] = {0.f, 0.f};

    // prologue: stage K/V tile 0; bond tile 0 into registers
#pragma unroll
    for (int i = 0; i < 4; ++i) {
        const int idx = i * 128 + t;
        const int row = idx >> 3, ch = idx & 7;
        const int chg = ch ^ (row & 7);
        gld16(kb + kvBase + (size_t)row * 64 + chg * 8, (char*)&Ks[0][0] + idx * 16);
        gld16(vtb + ((size_t)bh * 64 + row) * 2048 + chg * 8, (char*)&Vs[0][0] + idx * 16);
    }
    float4 bd[2][4], bdn[2][4];
#pragma unroll
    for (int qf = 0; qf < 2; ++qf)
#pragma unroll
        for (int kf = 0; kf < 4; ++kf)
            bd[qf][kf] = *(const float4*)&bondf[bondRow0 + (size_t)qf * 16 * 2048 + kf * 16 + g * 4];
    __syncthreads();

    for (int it = 0; it < 32; ++it) {
        const int cur = it & 1;
        const int kt = it * 64;
        // phase 1: issue K/V prefetch for t+1 (stays in flight through compute)
        if (it < 31) {
            const int kt2 = kt + 64;
#pragma unroll
            for (int i = 0; i < 4; ++i) {
                const int idx = i * 128 + t;
                const int row = idx >> 3, ch = idx & 7;
                const int chg = ch ^ (row & 7);
                gld16(kb + kvBase + (size_t)(kt2 + row) * 64 + chg * 8, (char*)&Ks[cur ^ 1][0] + idx * 16);
                gld16(vtb + ((size_t)bh * 64 + row) * 2048 + kt2 + chg * 8, (char*)&Vs[cur ^ 1][0] + idx * 16);
            }
            // phase 2: issue bond loads for t+1 into regs (wait lands after compute)
#pragma unroll
            for (int qf = 0; qf < 2; ++qf)
#pragma unroll
                for (int kf = 0; kf < 4; ++kf)
                    bdn[qf][kf] = *(const float4*)&bondf[bondRow0 + (size_t)qf * 16 * 2048 + kt2 + kf * 16 + g * 4];
        }

        // phase 3: QK^T for kf=0,1 (keys 0..31)
        f32x4 st[2][4];
#pragma unroll
        for (int qf = 0; qf < 2; ++qf)
#pragma unroll
            for (int kf = 0; kf < 4; ++kf) st[qf][kf] = zero4;
        {
            bf16x8 kfr[2][2];
#pragma unroll
            for (int kz = 0; kz < 2; ++kz)
#pragma unroll
                for (int kf = 0; kf < 2; ++kf)
                    kfr[kz][kf] = *(const bf16x8*)((const char*)&Ks[cur][0] +
                                    (kf * 16 + r) * 128 + (((kz * 4 + g) ^ sw) * 16));
            __builtin_amdgcn_s_setprio(1);
#pragma unroll
            for (int kz = 0; kz < 2; ++kz)
#pragma unroll
                for (int qf = 0; qf < 2; ++qf)
#pragma unroll
                    for (int kf = 0; kf < 2; ++kf)
                        st[qf][kf] = __builtin_amdgcn_mfma_f32_16x16x32_bf16(kfr[kz][kf], aq[qf][kz], st[qf][kf], 0, 0, 0);
            __builtin_amdgcn_s_setprio(0);
        }

        // phase 4: exp kf=0,1; write P-lo
#pragma unroll
        for (int qf = 0; qf < 2; ++qf)
#pragma unroll
            for (int kf = 0; kf < 2; ++kf) {
                const float p0 = __expf(st[qf][kf][0] * bd[qf][kf].x);
                const float p1 = __expf(st[qf][kf][1] * bd[qf][kf].y);
                const float p2 = __expf(st[qf][kf][2] * bd[qf][kf].z);
                const float p3 = __expf(st[qf][kf][3] * bd[qf][kf].w);
                sm[qf] += (p0 + p1) + (p2 + p3);
                uint2 pk;
                pk.x = packbf(p0, p1);
                pk.y = packbf(p2, p3);
                *(uint2*)((char*)&Ps[w][0] + (qf * 16 + r) * 128 + ((kf * 32 + g * 8) ^ (sw << 4))) = pk;
            }

        // phase 5: QK^T for kf=2,3 (MFMA hides P-lo write latency)
        {
            bf16x8 kfr[2][2];
#pragma unroll
            for (int kz = 0; kz < 2; ++kz)
#pragma unroll
                for (int kf = 0; kf < 2; ++kf)
                    kfr[kz][kf] = *(const bf16x8*)((const char*)&Ks[cur][0] +
                                    ((kf + 2) * 16 + r) * 128 + (((kz * 4 + g) ^ sw) * 16));
            __builtin_amdgcn_s_setprio(1);
#pragma unroll
            for (int kz = 0; kz < 2; ++kz)
#pragma unroll
                for (int qf = 0; qf < 2; ++qf)
#pragma unroll
                    for (int kf = 0; kf < 2; ++kf)
                        st[qf][kf + 2] = __builtin_amdgcn_mfma_f32_16x16x32_bf16(kfr[kz][kf], aq[qf][kz], st[qf][kf + 2], 0, 0, 0);
            __builtin_amdgcn_s_setprio(0);
        }

        // phase 6: PV kz=0 (keys 0..31, P-lo ready)
        {
            bf16x8 ap[2], bv_[4];
#pragma unroll
            for (int qf = 0; qf < 2; ++qf)
                ap[qf] = *(const bf16x8*)((const char*)&Ps[w][0] +
                            (qf * 16 + r) * 128 + ((g * 16) ^ (sw << 4)));
#pragma unroll
            for (int nf = 0; nf < 4; ++nf)
                bv_[nf] = *(const bf16x8*)((const char*)&Vs[cur][0] +
                            (nf * 16 + r) * 128 + ((g ^ sw) * 16));
            __builtin_amdgcn_s_setprio(1);
#pragma unroll
            for (int qf = 0; qf < 2; ++qf)
#pragma unroll
                for (int nf = 0; nf < 4; ++nf)
                    o[qf][nf] = __builtin_amdgcn_mfma_f32_16x16x32_bf16(ap[qf], bv_[nf], o[qf][nf], 0, 0, 0);
            __builtin_amdgcn_s_setprio(0);
        }

        // phase 7: exp kf=2,3; write P-hi
#pragma unroll
        for (int qf = 0; qf < 2; ++qf)
#pragma unroll
            for (int kf = 2; kf < 4; ++kf) {
                const float p0 = __expf(st[qf][kf][0] * bd[qf][kf].x);
                const float p1 = __expf(st[qf][kf][1] * bd[qf][kf].y);
                const float p2 = __expf(st[qf][kf][2] * bd[qf][kf].z);
                const float p3 = __expf(st[qf][kf][3] * bd[qf][kf].w);
                sm[qf] += (p0 + p1) + (p2 + p3);
                uint2 pk;
                pk.x = packbf(p0, p1);
                pk.y = packbf(p2, p3);
                *(uint2*)((char*)&Ps[w][0] + (qf * 16 + r) * 128 + ((kf * 32 + g * 8) ^ (sw << 4))) = pk;
            }

        // phase 8: PV kz=1 (keys 32..63)
        {
            bf16x8 ap[2], bv_[4];
#pragma unroll
            for (int qf = 0; qf < 2; ++qf)
                ap[qf] = *(const bf16x8*)((const char*)&Ps[w][0] +
                            (qf * 16 + r) * 128 + ((64 + g * 16) ^ (sw << 4)));
#pragma unroll
            for (int nf = 0; nf < 4; ++nf)
                bv_[nf] = *(const bf16x8*)((const char*)&Vs[cur][0] +
                            (nf * 16 + r) * 128 + (((4 + g) ^ sw) * 16));
            __builtin_amdgcn_s_setprio(1);
#pragma unroll
            for (int qf = 0; qf < 2; ++qf)
#pragma unroll
                for (int nf = 0; nf < 4; ++nf)
                    o[qf][nf] = __builtin_amdgcn_mfma_f32_16x16x32_bf16(ap[qf], bv_[nf], o[qf][nf], 0, 0, 0);
            __builtin_amdgcn_s_setprio(0);
        }

        // phase 9: rotate bond regs (forces the bond-load wait here, after compute)
        if (it < 31) {
#pragma unroll
            for (int qf = 0; qf < 2; ++qf)
#pragma unroll
                for (int kf = 0; kf < 4; ++kf)
                    bd[qf][kf] = bdn[qf][kf];
        }
        __syncthreads();
    }

    // final row-sum reduce across the 4 g-groups
#pragma unroll
    for (int qf = 0; qf < 2; ++qf) {
        sm[qf] += __shfl_xor(sm[qf], 16, 64);
        sm[qf] += __shfl_xor(sm[qf], 32, 64);
    }
    float* Lw = (float*)&Ps[w][0];
    if (g == 0) { Lw[r] = sm[0]; Lw[16 + r] = sm[1]; }
    __syncthreads();
    f32x4 lv[2];
    lv[0] = *(const f32x4*)&Lw[g * 4];
    lv[1] = *(const f32x4*)&Lw[16 + g * 4];

#pragma unroll
    for (int qf = 0; qf < 2; ++qf)
#pragma unroll
        for (int j = 0; j < 4; ++j) {
            const float inv = 1.f / lv[qf][j];
            const size_t orow = ((size_t)b * 2048 + q0 + qf * 16 + g * 4 + j) * 1024 + h * 64;
#pragma unroll
            for (int nf = 0; nf < 4; ++nf)
                attnout[orow + nf * 16 + r] = f2bf(o[qf][nf][j] * inv);
        }
}

// ---------------- launch ----------------

extern "C" void kernel_launch(void* const* d_in, const int* in_sizes, int n_in,
                              void* d_out, int out_size, void* d_ws, size_t ws_size,
                              hipStream_t stream) {
    (void)in_sizes; (void)n_in; (void)out_size; (void)ws_size;
    const float* x    = (const float*)d_in[0];
    const float* bond = (const float*)d_in[1];
    const float* Wq   = (const float*)d_in[2];
    const float* bq   = (const float*)d_in[3];
    const float* Wk   = (const float*)d_in[4];
    const float* bk   = (const float*)d_in[5];
    const float* Wv   = (const float*)d_in[6];
    const float* bv   = (const float*)d_in[7];
    const float* Wo   = (const float*)d_in[8];
    const float* bo   = (const float*)d_in[9];
    float* out = (float*)d_out;

    char* ws = (char*)d_ws;
    u16* xb      = (u16*)(ws);
    u16* wqkvt   = (u16*)(ws + 8388608);
    u16* wot     = (u16*)(ws + 14680064);
    u16* qb      = (u16*)(ws + 16777216);
    u16* kb_     = (u16*)(ws + 25165824);
    u16* vtb     = (u16*)(ws + 33554432);
    u16* attnout = (u16*)(ws + 58720256);

    dim3 tb(32, 8);
    transpose_bf16_kernel<<<dim3(32, 32), tb, 0, stream>>>(Wq, wqkvt);
    transpose_bf16_kernel<<<dim3(32, 32), tb, 0, stream>>>(Wk, wqkvt + 1024 * 1024);
    transpose_bf16_kernel<<<dim3(32, 32), tb, 0, stream>>>(Wv, wqkvt + 2 * 1024 * 1024);
    transpose_bf16_kernel<<<dim3(32, 32), tb, 0, stream>>>(Wo, wot);
    cvt_bf16_kernel<<<1024, 256, 0, stream>>>(x, xb, 4194304 / 4);

    gemm128<0><<<dim3(24, 32), 256, 0, stream>>>(xb, wqkvt, bq, bk, bv, qb, kb_, vtb, nullptr);
    attn_kernel<<<dim3(1024), 128, 0, stream>>>(qb, kb_, vtb, bond, attnout);
    gemm128<1><<<dim3(8, 32), 256, 0, stream>>>(attnout, wot, bo, nullptr, nullptr,
                                                nullptr, nullptr, nullptr, out);
}